// Round 3
// baseline (295.967 us; speedup 1.0000x reference)
//
#include <hip/hip_runtime.h>
#include <hip/hip_bf16.h>
#include <stdint.h>
#include <stddef.h>

// ---------- types ----------
typedef __bf16 b16;
typedef __bf16 b16x4 __attribute__((ext_vector_type(4)));
typedef __bf16 b16x8 __attribute__((ext_vector_type(8)));
typedef float  f32x4 __attribute__((ext_vector_type(4)));

#define LOG2E 1.4426950408889634f
#define QSCALE (0.125f * LOG2E)   // 1/sqrt(64) folded with log2(e): softmax in exp2 domain

#if __has_builtin(__builtin_amdgcn_exp2f)
#define EXP2F(x) __builtin_amdgcn_exp2f(x)
#else
#define EXP2F(x) exp2f(x)
#endif

typedef __attribute__((address_space(1))) void gvoid;
typedef __attribute__((address_space(3))) void svoid;

// async global->LDS, 16B per lane. LDS dest must be wave-uniform base + lane*16.
__device__ __forceinline__ void async_cp16(void* lds, const void* g) {
    __builtin_amdgcn_global_load_lds((gvoid*)(void*)g, (svoid*)lds, 16, 0, 0);
}

// ---------- kernel 1: x fp32 -> bf16 ----------
__global__ __launch_bounds__(256) void k_cvt_x(const float* __restrict__ x,
                                               b16* __restrict__ xb) {
    int i = (blockIdx.x * 256 + threadIdx.x) * 4;
    float4 v = *(const float4*)(x + i);
    b16x4 o = { (b16)v.x, (b16)v.y, (b16)v.z, (b16)v.w };
    *(b16x4*)(xb + i) = o;
}

// ---------- kernel 2: W[k][n] fp32 -> Wt[n][k] bf16 (per 32x32 tile) ----------
__global__ __launch_bounds__(256) void k_transpose(const float* __restrict__ Wq,
                                                   const float* __restrict__ Wk,
                                                   const float* __restrict__ Wv,
                                                   const float* __restrict__ Wo,
                                                   b16* __restrict__ WtQKV,
                                                   b16* __restrict__ Wot) {
    __shared__ float t[32][33];
    const int z = blockIdx.z;
    const float* W = (z == 0) ? Wq : (z == 1) ? Wk : (z == 2) ? Wv : Wo;
    const int k0 = blockIdx.x * 32, n0 = blockIdx.y * 32;
    const int tr = threadIdx.x >> 3, tc4 = (threadIdx.x & 7) * 4;
    float4 v = *(const float4*)(W + (size_t)(k0 + tr) * 1024 + n0 + tc4);
    t[tr][tc4 + 0] = v.x; t[tr][tc4 + 1] = v.y;
    t[tr][tc4 + 2] = v.z; t[tr][tc4 + 3] = v.w;
    __syncthreads();
    b16* dst = (z < 3) ? (WtQKV + ((size_t)z << 20)) : Wot;
    b16x4 o = { (b16)t[tc4 + 0][tr], (b16)t[tc4 + 1][tr],
                (b16)t[tc4 + 2][tr], (b16)t[tc4 + 3][tr] };
    *(b16x4*)(dst + (size_t)(n0 + tr) * 1024 + k0 + tc4) = o;
}

// ---------- GEMM 128x128 core, single-barrier double-buffered K-loop ----------
__device__ __forceinline__ void gemm_stage(const b16* __restrict__ Ab,
                                           const b16* __restrict__ Bb,
                                           b16* As, b16* Bs, int buf, int k0, int tid) {
    const int ci0 = tid, ci1 = tid + 256;
    b16* Ad = As + buf * 4096;
    b16* Bd = Bs + buf * 4096;
    async_cp16(Ad + ci0 * 8, Ab + (size_t)(ci0 >> 2) * 1024 + k0 + (ci0 & 3) * 8);
    async_cp16(Ad + ci1 * 8, Ab + (size_t)(ci1 >> 2) * 1024 + k0 + (ci1 & 3) * 8);
    async_cp16(Bd + ci0 * 8, Bb + (size_t)(ci0 >> 2) * 1024 + k0 + (ci0 & 3) * 8);
    async_cp16(Bd + ci1 * 8, Bb + (size_t)(ci1 >> 2) * 1024 + k0 + (ci1 & 3) * 8);
}

// As/Bs are [2][128*32]. One barrier per K-iter: stage issued AFTER barrier
// targets buf^1; vmcnt(0) at next barrier waits on loads a full iter old.
__device__ __forceinline__ void gemm128_core(const b16* __restrict__ Ab,
                                             const b16* __restrict__ Bb,
                                             b16* As, b16* Bs, int tid,
                                             f32x4 acc[4][4]) {
    const int lane = tid & 63, wave = tid >> 6;
    const int wm = wave & 1, wn = wave >> 1;
    const int quad = lane >> 4, lc = lane & 15;
    gemm_stage(Ab, Bb, As, Bs, 0, 0, tid);
    int cur = 0;
    for (int k0 = 0; k0 < 1024; k0 += 32) {
        __syncthreads();
        const int kn = (k0 + 32 < 1024) ? k0 + 32 : 0;   // wrap: harmless dead stage
        gemm_stage(Ab, Bb, As, Bs, cur ^ 1, kn, tid);
        const b16* Ac = As + cur * 4096;
        const b16* Bc = Bs + cur * 4096;
        b16x8 af[4], bfr[4];
#pragma unroll
        for (int mt = 0; mt < 4; ++mt)
            af[mt] = *(const b16x8*)(Ac + (wm * 64 + mt * 16 + lc) * 32 + quad * 8);
#pragma unroll
        for (int nt = 0; nt < 4; ++nt)
            bfr[nt] = *(const b16x8*)(Bc + (wn * 64 + nt * 16 + lc) * 32 + quad * 8);
#pragma unroll
        for (int mt = 0; mt < 4; ++mt)
#pragma unroll
            for (int nt = 0; nt < 4; ++nt)
                acc[mt][nt] = __builtin_amdgcn_mfma_f32_16x16x32_bf16(
                    af[mt], bfr[nt], acc[mt][nt], 0, 0, 0);
        cur ^= 1;
    }
}

// ---------- kernel 3: fused QKV projection ----------
__global__ __launch_bounds__(256, 3) void k_gemm_qkv(
    const b16* __restrict__ A, const b16* __restrict__ Bt,
    const float* __restrict__ bq, const float* __restrict__ bk,
    const float* __restrict__ bv,
    b16* __restrict__ Qg, b16* __restrict__ Kg, b16* __restrict__ Vtg) {
    __shared__ __align__(16) b16 As[2 * 128 * 32];
    __shared__ __align__(16) b16 Bs[2 * 128 * 32];
    const int bm = blockIdx.x, bn = blockIdx.y;
    const int tid = threadIdx.x;
    const int lane = tid & 63, wave = tid >> 6;
    const int wm = wave & 1, wn = wave >> 1;
    const int quad = lane >> 4, lc = lane & 15;

    f32x4 acc[4][4] = {};
    gemm128_core(A + (size_t)(bm * 128) * 1024, Bt + (size_t)(bn * 128) * 1024,
                 As, Bs, tid, acc);

    const int mat = bn >> 3;
    const float* bp = (mat == 0) ? bq : (mat == 1) ? bk : bv;
#pragma unroll
    for (int nt = 0; nt < 4; ++nt) {
        const int n = bn * 128 + wn * 64 + nt * 16 + lc;
        const int cm = n & 1023;
        const int h = cm >> 6, dh = cm & 63;
        const float bval = bp[cm];
#pragma unroll
        for (int mt = 0; mt < 4; ++mt) {
            const int m0 = bm * 128 + wm * 64 + mt * 16 + quad * 4;
            const int b = m0 >> 11;
            const int bh = b * 16 + h;
            const int s0 = m0 & 2047;
            if (mat == 2) {
                b16x4 o;
#pragma unroll
                for (int r = 0; r < 4; ++r) o[r] = (b16)(acc[mt][nt][r] + bval);
                *(b16x4*)(Vtg + (size_t)(bh * 64 + dh) * 2048 + s0) = o;
            } else if (mat == 0) {
#pragma unroll
                for (int r = 0; r < 4; ++r)
                    Qg[(size_t)(bh * 2048 + s0 + r) * 64 + dh] =
                        (b16)((acc[mt][nt][r] + bval) * QSCALE);
            } else {
#pragma unroll
                for (int r = 0; r < 4; ++r)
                    Kg[(size_t)(bh * 2048 + s0 + r) * 64 + dh] =
                        (b16)(acc[mt][nt][r] + bval);
            }
        }
    }
}

// ---------- kernel 4: flash attention ----------
// 256 q rows/block (4 waves x 64 q), 64-key tiles, np key-split parts.
// Single-barrier dbuf K/V staging; PV interleaved per 32-key half so the
// per-wave P buffer is 64x32 (stride 40 b16 keeps b64 stores / b128 reads
// bank-balanced). No-max exp2 softmax (logits bounded ~9 in base-2).
__global__ __launch_bounds__(256, 3) void k_flash(
    const b16* __restrict__ Qg, const b16* __restrict__ Kg,
    const b16* __restrict__ Vtg,
    float* __restrict__ Opart, float* __restrict__ lpart,
    b16* __restrict__ AO, int ktiles, int direct) {
    __shared__ __align__(16) b16 Ks[2][64 * 64];
    __shared__ __align__(16) b16 Vs[2][64 * 64];
    __shared__ __align__(16) b16 Ps[4][64 * 40];
    const int qb = blockIdx.x;        // 0..7 : 256-row q block
    const int bh = blockIdx.y;        // 0..31
    const int part = blockIdx.z;      // 0..np-1
    const int tid = threadIdx.x, lane = tid & 63, wave = tid >> 6;
    const int quad = lane >> 4, lc = lane & 15;

    // Q fragments (B-operand), 64 q rows per wave, resident all kernel
    const b16* Qbase = Qg + ((size_t)bh * 2048 + qb * 256 + wave * 64) * 64;
    b16x8 qf[4][2];
#pragma unroll
    for (int qt = 0; qt < 4; ++qt)
#pragma unroll
        for (int ch = 0; ch < 2; ++ch)
            qf[qt][ch] = *(const b16x8*)(Qbase + (qt * 16 + lc) * 64 + ch * 32 + quad * 8);

    f32x4 oacc[4][4] = {};
    float lsum[4] = {0.f, 0.f, 0.f, 0.f};

    const b16* Kbh = Kg + (size_t)bh * 2048 * 64;
    const b16* Vbh = Vtg + (size_t)bh * 64 * 2048;
    b16* Pw = Ps[wave];
    const int kt0 = part * ktiles, ktend = kt0 + ktiles;

    // staging helper (inlined twice): rows r=ci>>3, XOR chunk swizzle
    const int ciA = tid, ciB = tid + 256;
    const int rA = ciA >> 3, gA = (ciA & 7) ^ (rA & 7);
    const int rB = ciB >> 3, gB = (ciB & 7) ^ (rB & 7);

    // prologue: stage tile kt0 into buf 0
    {
        async_cp16(&Ks[0][ciA * 8], Kbh + (size_t)(kt0 * 64 + rA) * 64 + gA * 8);
        async_cp16(&Ks[0][ciB * 8], Kbh + (size_t)(kt0 * 64 + rB) * 64 + gB * 8);
        async_cp16(&Vs[0][ciA * 8], Vbh + (size_t)rA * 2048 + kt0 * 64 + gA * 8);
        async_cp16(&Vs[0][ciB * 8], Vbh + (size_t)rB * 2048 + kt0 * 64 + gB * 8);
    }
    int cur = 0;

    for (int kt = kt0; kt < ktend; ++kt) {
        __syncthreads();   // drains this buf's staging (vmcnt(0) on own loads)
        const int nk = (kt + 1 < ktend) ? kt + 1 : kt0;   // wrap: dead stage
        const int nb = cur ^ 1;
        async_cp16(&Ks[nb][ciA * 8], Kbh + (size_t)(nk * 64 + rA) * 64 + gA * 8);
        async_cp16(&Ks[nb][ciB * 8], Kbh + (size_t)(nk * 64 + rB) * 64 + gB * 8);
        async_cp16(&Vs[nb][ciA * 8], Vbh + (size_t)rA * 2048 + nk * 64 + gA * 8);
        async_cp16(&Vs[nb][ciB * 8], Vbh + (size_t)rB * 2048 + nk * 64 + gB * 8);

        const b16* Kc = Ks[cur];
        const b16* Vc = Vs[cur];
#pragma unroll
        for (int half = 0; half < 2; ++half) {
            // S^T for the 32 keys of this half; exp2; P into per-wave buffer
#pragma unroll
            for (int m2 = 0; m2 < 2; ++m2) {
                const int row = (half * 2 + m2) * 16 + lc;
                const b16x8 kf0 = *(const b16x8*)(Kc + row * 64 + ((quad) ^ (row & 7)) * 8);
                const b16x8 kf1 = *(const b16x8*)(Kc + row * 64 + ((4 + quad) ^ (row & 7)) * 8);
#pragma unroll
                for (int qt = 0; qt < 4; ++qt) {
                    f32x4 s = {};
                    s = __builtin_amdgcn_mfma_f32_16x16x32_bf16(kf0, qf[qt][0], s, 0, 0, 0);
                    s = __builtin_amdgcn_mfma_f32_16x16x32_bf16(kf1, qf[qt][1], s, 0, 0, 0);
                    const float e0 = EXP2F(s[0]), e1 = EXP2F(s[1]);
                    const float e2 = EXP2F(s[2]), e3 = EXP2F(s[3]);
                    lsum[qt] += (e0 + e1) + (e2 + e3);
                    b16x4 p = { (b16)e0, (b16)e1, (b16)e2, (b16)e3 };
                    *(b16x4*)(Pw + (qt * 16 + lc) * 40 + m2 * 16 + quad * 4) = p;
                }
            }
            // O += P(half) * V(half): A=P[q][k32], B=V rows from V^T tile
            b16x8 vf[4], pf[4];
#pragma unroll
            for (int dt = 0; dt < 4; ++dt) {
                const int row = dt * 16 + lc;
                vf[dt] = *(const b16x8*)(Vc + row * 64 + ((half * 4 + quad) ^ (row & 7)) * 8);
            }
#pragma unroll
            for (int mt = 0; mt < 4; ++mt)
                pf[mt] = *(const b16x8*)(Pw + (mt * 16 + lc) * 40 + quad * 8);
#pragma unroll
            for (int mt = 0; mt < 4; ++mt)
#pragma unroll
                for (int dt = 0; dt < 4; ++dt)
                    oacc[mt][dt] = __builtin_amdgcn_mfma_f32_16x16x32_bf16(
                        pf[mt], vf[dt], oacc[mt][dt], 0, 0, 0);
        }
        cur ^= 1;
    }

    // reduce l across quads (lane holds l for q = qt*16+lc)
#pragma unroll
    for (int qt = 0; qt < 4; ++qt) {
        lsum[qt] += __shfl_xor(lsum[qt], 16, 64);
        lsum[qt] += __shfl_xor(lsum[qt], 32, 64);
    }

    if (!direct) {
        float* Op = Opart + ((size_t)(part * 32 + bh) * 2048 + qb * 256 + wave * 64) * 64;
#pragma unroll
        for (int mt = 0; mt < 4; ++mt)
#pragma unroll
            for (int dt = 0; dt < 4; ++dt)
#pragma unroll
                for (int r = 0; r < 4; ++r)
                    Op[(mt * 16 + quad * 4 + r) * 64 + dt * 16 + lc] = oacc[mt][dt][r];
        if (quad == 0) {
            float* lp = lpart + (size_t)(part * 32 + bh) * 2048 + qb * 256 + wave * 64;
#pragma unroll
            for (int qt = 0; qt < 4; ++qt) lp[qt * 16 + lc] = lsum[qt];
        }
    } else {
        // single-part path: redistribute l via per-wave LDS, write AO directly
        float* Ls = (float*)(void*)Pw;    // P region dead now
        if (quad == 0) {
#pragma unroll
            for (int qt = 0; qt < 4; ++qt) Ls[qt * 16 + lc] = lsum[qt];
        }
        const int b = bh >> 4, h = bh & 15;
#pragma unroll
        for (int mt = 0; mt < 4; ++mt)
#pragma unroll
            for (int r = 0; r < 4; ++r) {
                const float inv = 1.0f / Ls[mt * 16 + quad * 4 + r];
                const int s = qb * 256 + wave * 64 + mt * 16 + quad * 4 + r;
#pragma unroll
                for (int dt = 0; dt < 4; ++dt)
                    AO[(size_t)(b * 2048 + s) * 1024 + h * 64 + dt * 16 + lc] =
                        (b16)(oacc[mt][dt][r] * inv);
            }
    }
}

// ---------- kernel 4b: merge partials: AO = sum(O_p) / sum(l_p) ----------
__global__ __launch_bounds__(256) void k_merge(const float* __restrict__ Opart,
                                               const float* __restrict__ lpart,
                                               b16* __restrict__ AO, int np) {
    const int bh = blockIdx.y;
    const int q = blockIdx.x * 16 + (threadIdx.x >> 4);
    const int d4 = (threadIdx.x & 15) * 4;
    const size_t qi = (size_t)bh * 2048 + q;
    f32x4 o = *(const f32x4*)(Opart + qi * 64 + d4);
    float l = lpart[qi];
    for (int p = 1; p < np; ++p) {
        o += *(const f32x4*)(Opart + (qi + (size_t)p * 32 * 2048) * 64 + d4);
        l += lpart[qi + (size_t)p * 32 * 2048];
    }
    const float inv = 1.0f / l;
    const int b = bh >> 4, h = bh & 15;
    b16x4 ob = { (b16)(o[0] * inv), (b16)(o[1] * inv),
                 (b16)(o[2] * inv), (b16)(o[3] * inv) };
    *(b16x4*)(AO + (size_t)(b * 2048 + q) * 1024 + h * 64 + d4) = ob;
}

// ---------- kernel 5: output projection, 64x128 tiles, dbuf core ----------
__global__ __launch_bounds__(256, 2) void k_gemm_out(
    const b16* __restrict__ A, const b16* __restrict__ Bt,
    const float* __restrict__ bo, float* __restrict__ out) {
    __shared__ __align__(16) b16 As[2 * 64 * 32];
    __shared__ __align__(16) b16 Bs[2 * 128 * 32];
    const int bm = blockIdx.x, bn = blockIdx.y;
    const int tid = threadIdx.x;
    const int lane = tid & 63, wave = tid >> 6;
    const int wm = wave & 1, wn = wave >> 1;
    const int quad = lane >> 4, lc = lane & 15;
    const b16* Ab = A + (size_t)(bm * 64) * 1024;
    const b16* Bb = Bt + (size_t)(bn * 128) * 1024;

    const int ci0 = tid, ci1 = tid + 256;
    // prologue stage
    async_cp16(&As[ci0 * 8], Ab + (size_t)(ci0 >> 2) * 1024 + (ci0 & 3) * 8);
    async_cp16(&Bs[ci0 * 8], Bb + (size_t)(ci0 >> 2) * 1024 + (ci0 & 3) * 8);
    async_cp16(&Bs[ci1 * 8], Bb + (size_t)(ci1 >> 2) * 1024 + (ci1 & 3) * 8);

    f32x4 acc[2][4] = {};
    int cur = 0;
    for (int k0 = 0; k0 < 1024; k0 += 32) {
        __syncthreads();
        const int kn = (k0 + 32 < 1024) ? k0 + 32 : 0;
        const int nb = cur ^ 1;
        async_cp16(&As[nb * 2048 + ci0 * 8], Ab + (size_t)(ci0 >> 2) * 1024 + kn + (ci0 & 3) * 8);
        async_cp16(&Bs[nb * 4096 + ci0 * 8], Bb + (size_t)(ci0 >> 2) * 1024 + kn + (ci0 & 3) * 8);
        async_cp16(&Bs[nb * 4096 + ci1 * 8], Bb + (size_t)(ci1 >> 2) * 1024 + kn + (ci1 & 3) * 8);
        const b16* Ac = &As[cur * 2048];
        const b16* Bc = &Bs[cur * 4096];
        b16x8 af[2], bfr[4];
#pragma unroll
        for (int mt = 0; mt < 2; ++mt)
            af[mt] = *(const b16x8*)(Ac + (wm * 32 + mt * 16 + lc) * 32 + quad * 8);
#pragma unroll
        for (int nt = 0; nt < 4; ++nt)
            bfr[nt] = *(const b16x8*)(Bc + (wn * 64 + nt * 16 + lc) * 32 + quad * 8);
#pragma unroll
        for (int mt = 0; mt < 2; ++mt)
#pragma unroll
            for (int nt = 0; nt < 4; ++nt)
                acc[mt][nt] = __builtin_amdgcn_mfma_f32_16x16x32_bf16(
                    af[mt], bfr[nt], acc[mt][nt], 0, 0, 0);
        cur ^= 1;
    }

#pragma unroll
    for (int nt = 0; nt < 4; ++nt) {
        const int n = bn * 128 + wn * 64 + nt * 16 + lc;
        const float bval = bo[n];
#pragma unroll
        for (int mt = 0; mt < 2; ++mt) {
            const int m0 = bm * 64 + wm * 32 + mt * 16 + quad * 4;
#pragma unroll
            for (int r = 0; r < 4; ++r)
                out[(size_t)(m0 + r) * 1024 + n] = acc[mt][nt][r] + bval;
        }
    }
}

// ---------- launcher ----------
extern "C" void kernel_launch(void* const* d_in, const int* in_sizes, int n_in,
                              void* d_out, int out_size, void* d_ws, size_t ws_size,
                              hipStream_t stream) {
    const float* x  = (const float*)d_in[0];
    const float* Wq = (const float*)d_in[1];
    const float* bq = (const float*)d_in[2];
    const float* Wk = (const float*)d_in[3];
    const float* bk = (const float*)d_in[4];
    const float* Wv = (const float*)d_in[5];
    const float* bv = (const float*)d_in[6];
    const float* Wo = (const float*)d_in[7];
    const float* bo = (const float*)d_in[8];
    float* out = (float*)d_out;

    char* ws = (char*)d_ws;
    const size_t MB = 1024 * 1024;
    b16* Xb  = (b16*)(ws);             // [4096][1024] bf16 (dead after qkv)
    b16* AO  = (b16*)(ws);             // [4096][1024] bf16 (overlay on Xb)
    b16* WtQ = (b16*)(ws + 8 * MB);    // [3072][1024] bf16
    b16* Wot = (b16*)(ws + 14 * MB);   // [1024][1024] bf16
    b16* Qg  = (b16*)(ws + 16 * MB);   // [32][2048][64] bf16 (pre-scaled)
    b16* Kg  = (b16*)(ws + 24 * MB);   // [32][2048][64] bf16
    b16* Vtg = (b16*)(ws + 32 * MB);   // [32][64][2048] bf16

    const size_t base = 40 * MB;
    int np = 1;
    if (ws_size >= base + 4 * 16 * MB + 4 * 256 * 1024) np = 4;
    else if (ws_size >= base + 2 * 16 * MB + 2 * 256 * 1024) np = 2;
    float* Opart = (float*)(ws + base);                          // [np][32][2048][64] f32
    float* lpart = (float*)(ws + base + (size_t)np * 16 * MB);   // [np][32][2048] f32
    const int direct = (np == 1);

    k_cvt_x<<<4096, 256, 0, stream>>>(x, Xb);
    k_transpose<<<dim3(32, 32, 4), 256, 0, stream>>>(Wq, Wk, Wv, Wo, WtQ, Wot);
    k_gemm_qkv<<<dim3(32, 24), 256, 0, stream>>>(Xb, WtQ, bq, bk, bv, Qg, Kg, Vtg);
    k_flash<<<dim3(8, 32, np), 256, 0, stream>>>(Qg, Kg, Vtg, Opart, lpart, AO,
                                                 32 / np, direct);
    if (!direct)
        k_merge<<<dim3(128, 32), 256, 0, stream>>>(Opart, lpart, AO, np);
    k_gemm_out<<<dim3(64, 8), 256, 0, stream>>>(AO, Wot, bo, out);
}

// Round 4
// 282.940 us; speedup vs baseline: 1.0460x; 1.0460x over previous
//
#include <hip/hip_runtime.h>
#include <hip/hip_bf16.h>
#include <stdint.h>
#include <stddef.h>

// ---------- types ----------
typedef __bf16 b16;
typedef __bf16 b16x4 __attribute__((ext_vector_type(4)));
typedef __bf16 b16x8 __attribute__((ext_vector_type(8)));
typedef short  s16x4 __attribute__((ext_vector_type(4)));
typedef float  f32x4 __attribute__((ext_vector_type(4)));

#define LOG2E 1.4426950408889634f
#define QSCALE (0.125f * LOG2E)   // 1/sqrt(64) folded with log2(e): softmax in exp2 domain

#if __has_builtin(__builtin_amdgcn_exp2f)
#define EXP2F(x) __builtin_amdgcn_exp2f(x)
#else
#define EXP2F(x) exp2f(x)
#endif

typedef __attribute__((address_space(1))) void gvoid;
typedef __attribute__((address_space(3))) void svoid;

// async global->LDS, 16B per lane. LDS dest must be wave-uniform base + lane*16.
__device__ __forceinline__ void async_cp16(void* lds, const void* g) {
    __builtin_amdgcn_global_load_lds((gvoid*)(void*)g, (svoid*)lds, 16, 0, 0);
}

// ---------- kernel 1: x fp32 -> bf16 ----------
__global__ __launch_bounds__(256) void k_cvt_x(const float* __restrict__ x,
                                               b16* __restrict__ xb) {
    int i = (blockIdx.x * 256 + threadIdx.x) * 4;
    float4 v = *(const float4*)(x + i);
    b16x4 o = { (b16)v.x, (b16)v.y, (b16)v.z, (b16)v.w };
    *(b16x4*)(xb + i) = o;
}

// ---------- kernel 2: W[k][n] fp32 -> Wt[n][k] bf16 (per 32x32 tile) ----------
__global__ __launch_bounds__(256) void k_transpose(const float* __restrict__ Wq,
                                                   const float* __restrict__ Wk,
                                                   const float* __restrict__ Wv,
                                                   const float* __restrict__ Wo,
                                                   b16* __restrict__ WtQKV,
                                                   b16* __restrict__ Wot) {
    __shared__ float t[32][33];
    const int z = blockIdx.z;
    const float* W = (z == 0) ? Wq : (z == 1) ? Wk : (z == 2) ? Wv : Wo;
    const int k0 = blockIdx.x * 32, n0 = blockIdx.y * 32;
    const int tr = threadIdx.x >> 3, tc4 = (threadIdx.x & 7) * 4;
    float4 v = *(const float4*)(W + (size_t)(k0 + tr) * 1024 + n0 + tc4);
    t[tr][tc4 + 0] = v.x; t[tr][tc4 + 1] = v.y;
    t[tr][tc4 + 2] = v.z; t[tr][tc4 + 3] = v.w;
    __syncthreads();
    b16* dst = (z < 3) ? (WtQKV + ((size_t)z << 20)) : Wot;
    b16x4 o = { (b16)t[tc4 + 0][tr], (b16)t[tc4 + 1][tr],
                (b16)t[tc4 + 2][tr], (b16)t[tc4 + 3][tr] };
    *(b16x4*)(dst + (size_t)(n0 + tr) * 1024 + k0 + tc4) = o;
}

// ---------- GEMM 128x128 core, single-barrier double-buffered K-loop ----------
__device__ __forceinline__ void gemm_stage(const b16* __restrict__ Ab,
                                           const b16* __restrict__ Bb,
                                           b16* As, b16* Bs, int buf, int k0, int tid) {
    const int ci0 = tid, ci1 = tid + 256;
    b16* Ad = As + buf * 4096;
    b16* Bd = Bs + buf * 4096;
    async_cp16(Ad + ci0 * 8, Ab + (size_t)(ci0 >> 2) * 1024 + k0 + (ci0 & 3) * 8);
    async_cp16(Ad + ci1 * 8, Ab + (size_t)(ci1 >> 2) * 1024 + k0 + (ci1 & 3) * 8);
    async_cp16(Bd + ci0 * 8, Bb + (size_t)(ci0 >> 2) * 1024 + k0 + (ci0 & 3) * 8);
    async_cp16(Bd + ci1 * 8, Bb + (size_t)(ci1 >> 2) * 1024 + k0 + (ci1 & 3) * 8);
}

// One barrier per K-iter: stage issued AFTER barrier targets buf^1; the
// vmcnt(0) at the next barrier waits on loads a full compute window old.
__device__ __forceinline__ void gemm128_core(const b16* __restrict__ Ab,
                                             const b16* __restrict__ Bb,
                                             b16* As, b16* Bs, int tid,
                                             f32x4 acc[4][4]) {
    const int lane = tid & 63, wave = tid >> 6;
    const int wm = wave & 1, wn = wave >> 1;
    const int quad = lane >> 4, lc = lane & 15;
    gemm_stage(Ab, Bb, As, Bs, 0, 0, tid);
    int cur = 0;
    for (int k0 = 0; k0 < 1024; k0 += 32) {
        __syncthreads();
        const int kn = (k0 + 32 < 1024) ? k0 + 32 : 0;   // wrap: harmless dead stage
        gemm_stage(Ab, Bb, As, Bs, cur ^ 1, kn, tid);
        const b16* Ac = As + cur * 4096;
        const b16* Bc = Bs + cur * 4096;
        b16x8 af[4], bfr[4];
#pragma unroll
        for (int mt = 0; mt < 4; ++mt)
            af[mt] = *(const b16x8*)(Ac + (wm * 64 + mt * 16 + lc) * 32 + quad * 8);
#pragma unroll
        for (int nt = 0; nt < 4; ++nt)
            bfr[nt] = *(const b16x8*)(Bc + (wn * 64 + nt * 16 + lc) * 32 + quad * 8);
#pragma unroll
        for (int mt = 0; mt < 4; ++mt)
#pragma unroll
            for (int nt = 0; nt < 4; ++nt)
                acc[mt][nt] = __builtin_amdgcn_mfma_f32_16x16x32_bf16(
                    af[mt], bfr[nt], acc[mt][nt], 0, 0, 0);
        cur ^= 1;
    }
}

// ---------- kernel 3: fused QKV projection ----------
__global__ __launch_bounds__(256, 3) void k_gemm_qkv(
    const b16* __restrict__ A, const b16* __restrict__ Bt,
    const float* __restrict__ bq, const float* __restrict__ bk,
    const float* __restrict__ bv,
    b16* __restrict__ Qg, b16* __restrict__ Kg, b16* __restrict__ Vtg) {
    __shared__ __align__(16) b16 As[2 * 128 * 32];
    __shared__ __align__(16) b16 Bs[2 * 128 * 32];
    const int bm = blockIdx.x, bn = blockIdx.y;
    const int tid = threadIdx.x;
    const int lane = tid & 63, wave = tid >> 6;
    const int wm = wave & 1, wn = wave >> 1;
    const int quad = lane >> 4, lc = lane & 15;

    f32x4 acc[4][4] = {};
    gemm128_core(A + (size_t)(bm * 128) * 1024, Bt + (size_t)(bn * 128) * 1024,
                 As, Bs, tid, acc);

    const int mat = bn >> 3;
    const float* bp = (mat == 0) ? bq : (mat == 1) ? bk : bv;
#pragma unroll
    for (int nt = 0; nt < 4; ++nt) {
        const int n = bn * 128 + wn * 64 + nt * 16 + lc;
        const int cm = n & 1023;
        const int h = cm >> 6, dh = cm & 63;
        const float bval = bp[cm];
#pragma unroll
        for (int mt = 0; mt < 4; ++mt) {
            const int m0 = bm * 128 + wm * 64 + mt * 16 + quad * 4;
            const int b = m0 >> 11;
            const int bh = b * 16 + h;
            const int s0 = m0 & 2047;
            if (mat == 2) {
                b16x4 o;
#pragma unroll
                for (int r = 0; r < 4; ++r) o[r] = (b16)(acc[mt][nt][r] + bval);
                *(b16x4*)(Vtg + (size_t)(bh * 64 + dh) * 2048 + s0) = o;
            } else if (mat == 0) {
#pragma unroll
                for (int r = 0; r < 4; ++r)
                    Qg[(size_t)(bh * 2048 + s0 + r) * 64 + dh] =
                        (b16)((acc[mt][nt][r] + bval) * QSCALE);
            } else {
#pragma unroll
                for (int r = 0; r < 4; ++r)
                    Kg[(size_t)(bh * 2048 + s0 + r) * 64 + dh] =
                        (b16)(acc[mt][nt][r] + bval);
            }
        }
    }
}

// ---------- kernel 4: flash attention, P never touches LDS ----------
// S^T = K*Q^T via 16x16x32 (D: key=quad*4+r, q=lc); exp2 in-register; the
// packed bf16x4 IS the B-operand layout of mfma_f32_16x16x16_bf16 (k=quad*4+j),
// so O^T = V^T * P^T accumulates directly from registers. LDS per 64-key tile
// drops 32->16 KB (K+V only). Grid: bh on x so the 8 qb blocks sharing one
// head's K/V land on the same XCD (i%8) -> K/V served from that XCD's L2.
__global__ __launch_bounds__(256, 3) void k_flash(
    const b16* __restrict__ Qg, const b16* __restrict__ Kg,
    const b16* __restrict__ Vtg,
    float* __restrict__ Opart, float* __restrict__ lpart,
    b16* __restrict__ AO, int ktiles, int direct) {
    __shared__ __align__(16) b16 Ks[2][64 * 64];
    __shared__ __align__(16) b16 Vs[2][64 * 64];
    const int bh = blockIdx.x;        // 0..31  (x-fastest => same-bh blocks share XCD)
    const int qb = blockIdx.y;        // 0..7 : 256-row q block
    const int part = blockIdx.z;      // 0..np-1
    const int tid = threadIdx.x, lane = tid & 63, wave = tid >> 6;
    const int quad = lane >> 4, lc = lane & 15;

    // Q fragments (B-operand of 16x16x32), 64 q rows per wave, resident all kernel
    const b16* Qbase = Qg + ((size_t)bh * 2048 + qb * 256 + wave * 64) * 64;
    b16x8 qf[4][2];
#pragma unroll
    for (int qt = 0; qt < 4; ++qt)
#pragma unroll
        for (int ch = 0; ch < 2; ++ch)
            qf[qt][ch] = *(const b16x8*)(Qbase + (qt * 16 + lc) * 64 + ch * 32 + quad * 8);

    // oacc[dt][qt] holds O^T: d = dt*16 + quad*4 + r, q = qt*16 + lc
    f32x4 oacc[4][4] = {};
    float lsum[4] = {0.f, 0.f, 0.f, 0.f};

    const b16* Kbh = Kg + (size_t)bh * 2048 * 64;
    const b16* Vbh = Vtg + (size_t)bh * 64 * 2048;
    const int kt0 = part * ktiles, ktend = kt0 + ktiles;

    const int ciA = tid, ciB = tid + 256;
    const int rA = ciA >> 3, gA = (ciA & 7) ^ (rA & 7);   // XOR chunk swizzle
    const int rB = ciB >> 3, gB = (ciB & 7) ^ (rB & 7);

    // prologue: stage tile kt0 into buf 0
    async_cp16(&Ks[0][ciA * 8], Kbh + (size_t)(kt0 * 64 + rA) * 64 + gA * 8);
    async_cp16(&Ks[0][ciB * 8], Kbh + (size_t)(kt0 * 64 + rB) * 64 + gB * 8);
    async_cp16(&Vs[0][ciA * 8], Vbh + (size_t)rA * 2048 + kt0 * 64 + gA * 8);
    async_cp16(&Vs[0][ciB * 8], Vbh + (size_t)rB * 2048 + kt0 * 64 + gB * 8);
    int cur = 0;

    for (int kt = kt0; kt < ktend; ++kt) {
        __syncthreads();
        const int nk = (kt + 1 < ktend) ? kt + 1 : kt0;   // wrap: dead stage
        const int nb = cur ^ 1;
        async_cp16(&Ks[nb][ciA * 8], Kbh + (size_t)(nk * 64 + rA) * 64 + gA * 8);
        async_cp16(&Ks[nb][ciB * 8], Kbh + (size_t)(nk * 64 + rB) * 64 + gB * 8);
        async_cp16(&Vs[nb][ciA * 8], Vbh + (size_t)rA * 2048 + nk * 64 + gA * 8);
        async_cp16(&Vs[nb][ciB * 8], Vbh + (size_t)rB * 2048 + nk * 64 + gB * 8);

        const b16* Kc = Ks[cur];
        const b16* Vc = Vs[cur];
#pragma unroll
        for (int m = 0; m < 4; ++m) {          // 16-key block
            const int row = m * 16 + lc;
            const b16x8 kf0 = *(const b16x8*)(Kc + row * 64 + ((quad) ^ (row & 7)) * 8);
            const b16x8 kf1 = *(const b16x8*)(Kc + row * 64 + ((4 + quad) ^ (row & 7)) * 8);

            s16x4 pb[4];
#pragma unroll
            for (int qt = 0; qt < 4; ++qt) {
                f32x4 s = {};
                s = __builtin_amdgcn_mfma_f32_16x16x32_bf16(kf0, qf[qt][0], s, 0, 0, 0);
                s = __builtin_amdgcn_mfma_f32_16x16x32_bf16(kf1, qf[qt][1], s, 0, 0, 0);
                const float e0 = EXP2F(s[0]), e1 = EXP2F(s[1]);
                const float e2 = EXP2F(s[2]), e3 = EXP2F(s[3]);
                lsum[qt] += (e0 + e1) + (e2 + e3);
                b16x4 p = { (b16)e0, (b16)e1, (b16)e2, (b16)e3 };
                pb[qt] = __builtin_bit_cast(s16x4, p);
            }
            // V^T fragments for key-step m: A[m=d][k=quad*4+j] -> b64 reads
            s16x4 vf[4];
#pragma unroll
            for (int dt = 0; dt < 4; ++dt) {
                const int vrow = dt * 16 + lc;
                const int chunk = (m * 2 + (quad >> 1)) ^ (vrow & 7);
                vf[dt] = *(const s16x4*)(Vc + vrow * 64 + chunk * 8 + (quad & 1) * 4);
            }
#pragma unroll
            for (int dt = 0; dt < 4; ++dt)
#pragma unroll
                for (int qt = 0; qt < 4; ++qt)
                    oacc[dt][qt] = __builtin_amdgcn_mfma_f32_16x16x16bf16_1k(
                        vf[dt], pb[qt], oacc[dt][qt], 0, 0, 0);
        }
        cur ^= 1;
    }

    // reduce l across quads (lane lc holds l for q = qt*16+lc after this)
#pragma unroll
    for (int qt = 0; qt < 4; ++qt) {
        lsum[qt] += __shfl_xor(lsum[qt], 16, 64);
        lsum[qt] += __shfl_xor(lsum[qt], 32, 64);
    }

    if (!direct) {
        // Opart row q, 64 d; lane writes f32x4 at (q=qt*16+lc, d=dt*16+quad*4)
        float* Op = Opart + ((size_t)(part * 32 + bh) * 2048 + qb * 256 + wave * 64) * 64;
#pragma unroll
        for (int qt = 0; qt < 4; ++qt)
#pragma unroll
            for (int dt = 0; dt < 4; ++dt)
                *(f32x4*)(Op + (qt * 16 + lc) * 64 + dt * 16 + quad * 4) = oacc[dt][qt];
        if (quad == 0) {
            float* lp = lpart + (size_t)(part * 32 + bh) * 2048 + qb * 256 + wave * 64;
#pragma unroll
            for (int qt = 0; qt < 4; ++qt) lp[qt * 16 + lc] = lsum[qt];
        }
    } else {
        // direct: lane's q = lc matches lsum's q -> no redistribution needed
        const int b = bh >> 4, h = bh & 15;
#pragma unroll
        for (int qt = 0; qt < 4; ++qt) {
            const float inv = 1.0f / lsum[qt];
            const int s = qb * 256 + wave * 64 + qt * 16 + lc;
#pragma unroll
            for (int dt = 0; dt < 4; ++dt) {
                b16x4 ob = { (b16)(oacc[dt][qt][0] * inv), (b16)(oacc[dt][qt][1] * inv),
                             (b16)(oacc[dt][qt][2] * inv), (b16)(oacc[dt][qt][3] * inv) };
                *(b16x4*)(AO + (size_t)(b * 2048 + s) * 1024 + h * 64 + dt * 16 + quad * 4) = ob;
            }
        }
    }
}

// ---------- kernel 4b: merge partials: AO = sum(O_p) / sum(l_p) ----------
__global__ __launch_bounds__(256) void k_merge(const float* __restrict__ Opart,
                                               const float* __restrict__ lpart,
                                               b16* __restrict__ AO, int np) {
    const int bh = blockIdx.y;
    const int q = blockIdx.x * 16 + (threadIdx.x >> 4);
    const int d4 = (threadIdx.x & 15) * 4;
    const size_t qi = (size_t)bh * 2048 + q;
    f32x4 o = *(const f32x4*)(Opart + qi * 64 + d4);
    float l = lpart[qi];
    for (int p = 1; p < np; ++p) {
        o += *(const f32x4*)(Opart + (qi + (size_t)p * 32 * 2048) * 64 + d4);
        l += lpart[qi + (size_t)p * 32 * 2048];
    }
    const float inv = 1.0f / l;
    const int b = bh >> 4, h = bh & 15;
    b16x4 ob = { (b16)(o[0] * inv), (b16)(o[1] * inv),
                 (b16)(o[2] * inv), (b16)(o[3] * inv) };
    *(b16x4*)(AO + (size_t)(b * 2048 + q) * 1024 + h * 64 + d4) = ob;
}

// ---------- kernel 5: output projection, 64x128 tiles, dbuf core ----------
__global__ __launch_bounds__(256, 2) void k_gemm_out(
    const b16* __restrict__ A, const b16* __restrict__ Bt,
    const float* __restrict__ bo, float* __restrict__ out) {
    __shared__ __align__(16) b16 As[2 * 64 * 32];
    __shared__ __align__(16) b16 Bs[2 * 128 * 32];
    const int bm = blockIdx.x, bn = blockIdx.y;
    const int tid = threadIdx.x;
    const int lane = tid & 63, wave = tid >> 6;
    const int wm = wave & 1, wn = wave >> 1;
    const int quad = lane >> 4, lc = lane & 15;
    const b16* Ab = A + (size_t)(bm * 64) * 1024;
    const b16* Bb = Bt + (size_t)(bn * 128) * 1024;

    const int ci0 = tid, ci1 = tid + 256;
    async_cp16(&As[ci0 * 8], Ab + (size_t)(ci0 >> 2) * 1024 + (ci0 & 3) * 8);
    async_cp16(&Bs[ci0 * 8], Bb + (size_t)(ci0 >> 2) * 1024 + (ci0 & 3) * 8);
    async_cp16(&Bs[ci1 * 8], Bb + (size_t)(ci1 >> 2) * 1024 + (ci1 & 3) * 8);

    f32x4 acc[2][4] = {};
    int cur = 0;
    for (int k0 = 0; k0 < 1024; k0 += 32) {
        __syncthreads();
        const int kn = (k0 + 32 < 1024) ? k0 + 32 : 0;
        const int nb = cur ^ 1;
        async_cp16(&As[nb * 2048 + ci0 * 8], Ab + (size_t)(ci0 >> 2) * 1024 + kn + (ci0 & 3) * 8);
        async_cp16(&Bs[nb * 4096 + ci0 * 8], Bb + (size_t)(ci0 >> 2) * 1024 + kn + (ci0 & 3) * 8);
        async_cp16(&Bs[nb * 4096 + ci1 * 8], Bb + (size_t)(ci1 >> 2) * 1024 + kn + (ci1 & 3) * 8);
        const b16* Ac = &As[cur * 2048];
        const b16* Bc = &Bs[cur * 4096];
        b16x8 af[2], bfr[4];
#pragma unroll
        for (int mt = 0; mt < 2; ++mt)
            af[mt] = *(const b16x8*)(Ac + (wm * 32 + mt * 16 + lc) * 32 + quad * 8);
#pragma unroll
        for (int nt = 0; nt < 4; ++nt)
            bfr[nt] = *(const b16x8*)(Bc + (wn * 64 + nt * 16 + lc) * 32 + quad * 8);
#pragma unroll
        for (int mt = 0; mt < 2; ++mt)
#pragma unroll
            for (int nt = 0; nt < 4; ++nt)
                acc[mt][nt] = __builtin_amdgcn_mfma_f32_16x16x32_bf16(
                    af[mt], bfr[nt], acc[mt][nt], 0, 0, 0);
        cur ^= 1;
    }

#pragma unroll
    for (int nt = 0; nt < 4; ++nt) {
        const int n = bn * 128 + wn * 64 + nt * 16 + lc;
        const float bval = bo[n];
#pragma unroll
        for (int mt = 0; mt < 2; ++mt) {
            const int m0 = bm * 64 + wm * 32 + mt * 16 + quad * 4;
#pragma unroll
            for (int r = 0; r < 4; ++r)
                out[(size_t)(m0 + r) * 1024 + n] = acc[mt][nt][r] + bval;
        }
    }
}

// ---------- launcher ----------
extern "C" void kernel_launch(void* const* d_in, const int* in_sizes, int n_in,
                              void* d_out, int out_size, void* d_ws, size_t ws_size,
                              hipStream_t stream) {
    const float* x  = (const float*)d_in[0];
    const float* Wq = (const float*)d_in[1];
    const float* bq = (const float*)d_in[2];
    const float* Wk = (const float*)d_in[3];
    const float* bk = (const float*)d_in[4];
    const float* Wv = (const float*)d_in[5];
    const float* bv = (const float*)d_in[6];
    const float* Wo = (const float*)d_in[7];
    const float* bo = (const float*)d_in[8];
    float* out = (float*)d_out;

    char* ws = (char*)d_ws;
    const size_t MB = 1024 * 1024;
    b16* Xb  = (b16*)(ws);             // [4096][1024] bf16 (dead after qkv)
    b16* AO  = (b16*)(ws);             // [4096][1024] bf16 (overlay on Xb)
    b16* WtQ = (b16*)(ws + 8 * MB);    // [3072][1024] bf16
    b16* Wot = (b16*)(ws + 14 * MB);   // [1024][1024] bf16
    b16* Qg  = (b16*)(ws + 16 * MB);   // [32][2048][64] bf16 (pre-scaled)
    b16* Kg  = (b16*)(ws + 24 * MB);   // [32][2048][64] bf16
    b16* Vtg = (b16*)(ws + 32 * MB);   // [32][64][2048] bf16

    const size_t base = 40 * MB;
    const int np = (ws_size >= base + 2 * 16 * MB + 2 * 256 * 1024) ? 2 : 1;
    float* Opart = (float*)(ws + base);                          // [np][32][2048][64] f32
    float* lpart = (float*)(ws + base + (size_t)np * 16 * MB);   // [np][32][2048] f32
    const int direct = (np == 1);

    k_cvt_x<<<4096, 256, 0, stream>>>(x, Xb);
    k_transpose<<<dim3(32, 32, 4), 256, 0, stream>>>(Wq, Wk, Wv, Wo, WtQ, Wot);
    k_gemm_qkv<<<dim3(32, 24), 256, 0, stream>>>(Xb, WtQ, bq, bk, bv, Qg, Kg, Vtg);
    k_flash<<<dim3(32, 8, np), 256, 0, stream>>>(Qg, Kg, Vtg, Opart, lpart, AO,
                                                 32 / np, direct);
    if (!direct)
        k_merge<<<dim3(128, 32), 256, 0, stream>>>(Opart, lpart, AO, np);
    k_gemm_out<<<dim3(64, 8), 256, 0, stream>>>(AO, Wot, bo, out);
}